// Round 1
// baseline (877.059 us; speedup 1.0000x reference)
//
#include <hip/hip_runtime.h>
#include <stdint.h>

#define B_   4
#define T_   1024
#define V_   32000
#define K_   50000
#define N_   (B_*(T_-1))        // 4092 pair-positions
#define TPB  1024
#define U_   49                  // ceil(K_/TPB)
#define KP   (TPB*U_)            // 50176 padded K
#define POS_PER_BLK 16
#define G1   ((N_ + POS_PER_BLK - 1)/POS_PER_BLK)   // 256 blocks = 1/CU (125KB LDS)
#define EPSTGT 1e-8f
#define EPSMOD 1e-12f
#define W4   (V_/4)              // 8000 float4 per row
#define NGRP (KP/64)             // 784 gather groups of 64 lanes
#define SCAP (2*NGRP)            // 1568: structured capacity per a-bank bin
#define PINV 0xFFFFFFFFu

// ---------- helpers ----------
__device__ __forceinline__ uint32_t bf16rne(float x) {
    uint32_t u = __float_as_uint(x);
    u += 0x7FFFu + ((u >> 16) & 1u);
    return u >> 16;
}
__device__ __forceinline__ uint2 pack4(float4 v) {
    uint2 pk;
    pk.x = bf16rne(v.x) | (bf16rne(v.y) << 16);
    pk.y = bf16rne(v.z) | (bf16rne(v.w) << 16);
    return pk;
}
// synchronous stage: fp32 global row -> bf16 LDS row (prologue / batch-boundary only)
__device__ __forceinline__ void stage_row(const float* __restrict__ probs, int r,
                                          ushort* dst, int tid) {
    const float4* src = (const float4*)(probs + (size_t)r * V_);
    for (int i = tid; i < W4; i += TPB) {
        *(uint2*)(dst + i * 4) = pack4(src[i]);
    }
}

// gather one pair: 2 LDS bf16 reads + fma
#define GATHER(pkv, accv) do {                                          \
    uint32_t ao_ = (pkv) >> 16, bo_ = (pkv) & 0xFFFFu;                  \
    ushort av_ = *(const ushort*)(rp + ao_);                            \
    ushort bv_ = *(const ushort*)(rq + bo_);                            \
    accv = fmaf(__uint_as_float((uint32_t)av_ << 16),                   \
                __uint_as_float((uint32_t)bv_ << 16), accv);            \
} while (0)

// ---------- kernel 0: bank-aware pair permutation ----------
// Slot s = group*64 + lane, group = wave-instruction granule of k_main's gather.
// Counting-sort pairs by a-bank (a>>1)&31 -> lane w and w+32 carry bin w:
//   every a-read instruction is exactly 2-way per bank (free, m136).
// Within each bin, order by b-bank and rotate bin w by w/32 of its length:
//   each group samples 32 staggered b-quantiles -> b-reads ~2-way as well.
// Bin overflow past SCAP spills into the pad holes (few hundred items).
__global__ __launch_bounds__(1024) void k_perm(const int* __restrict__ pairs,
                                               uint32_t* __restrict__ ppk,
                                               uint32_t* __restrict__ perm,
                                               uint32_t* __restrict__ ovf,
                                               uint32_t* __restrict__ holes) {
    __shared__ uint32_t hist[32][32];
    __shared__ uint32_t boff[32][32];
    __shared__ uint32_t cnt[32][32];
    __shared__ uint32_t binc[32], rot[32];
    __shared__ uint32_t novf, nhole;
    const int tid = threadIdx.x;

    ((uint32_t*)hist)[tid] = 0;          // 1024 cells exactly
    if (tid == 0) { novf = 0; nhole = 0; }
    __syncthreads();

    // pass 1: (a-bank, b-bank) histogram
    for (int k = tid; k < K_; k += 1024) {
        uint32_t a = (uint32_t)pairs[2 * k];
        uint32_t b = (uint32_t)pairs[2 * k + 1];
        atomicAdd(&hist[(a >> 1) & 31][(b >> 1) & 31], 1u);
    }
    __syncthreads();

    // prefix within each a-bin (b-bank order), bin counts, rotations
    if (tid < 32) {
        uint32_t s = 0;
        for (int j = 0; j < 32; ++j) { boff[tid][j] = s; s += hist[tid][j]; }
        binc[tid] = s;
        rot[tid] = ((uint32_t)tid * s) >> 5;     // w/32 of bin length
    }
    __syncthreads();
    ((uint32_t*)cnt)[tid] = 0;
    // init output: pad slots gather offset 0 (harmless), perm invalid
    for (int s = tid; s < KP; s += 1024) { ppk[s] = 0; perm[s] = PINV; }
    __syncthreads();

    // pass 2: scatter
    for (int k = tid; k < K_; k += 1024) {
        uint32_t a = (uint32_t)pairs[2 * k];
        uint32_t b = (uint32_t)pairs[2 * k + 1];
        uint32_t aw = (a >> 1) & 31, bw = (b >> 1) & 31;
        uint32_t j = boff[aw][bw] + atomicAdd(&cnt[aw][bw], 1u);
        uint32_t c = binc[aw];
        uint32_t jp = j + rot[aw]; if (jp >= c) jp -= c;
        uint32_t pk = ((a * 2u) << 16) | (b * 2u);
        if (jp < SCAP) {
            uint32_t s = ((jp >> 1) << 6) + aw + ((jp & 1u) << 5);
            ppk[s] = pk; perm[s] = (uint32_t)k;
        } else {
            uint32_t i = atomicAdd(&novf, 1u);
            ovf[2 * i] = pk; ovf[2 * i + 1] = (uint32_t)k;
        }
    }
    __syncthreads();

    // collect holes (pads + underfull tail groups); nhole >= novf by counting
    for (int s = tid; s < KP; s += 1024) {
        if (perm[s] == PINV) { uint32_t i = atomicAdd(&nhole, 1u); holes[i] = (uint32_t)s; }
    }
    __syncthreads();
    for (uint32_t i = tid; i < novf; i += 1024) {
        uint32_t s = holes[i];
        ppk[s] = ovf[2 * i]; perm[s] = ovf[2 * i + 1];
    }
}

// ---------- kernel 0b: n_pairs from mask ----------
__global__ void k_mask(const unsigned char* __restrict__ mask, float* __restrict__ scalars) {
    __shared__ int red[16];
    int tid = threadIdx.x;
    int cnt = 0;
    for (int n = tid; n < N_; n += 1024) {
        int b = n / (T_ - 1);
        int t = n - b * (T_ - 1);
        int r = b * T_ + t;
        cnt += (mask[r] && mask[r + 1]) ? 1 : 0;
    }
    for (int off = 32; off > 0; off >>= 1) cnt += __shfl_down(cnt, off, 64);
    int wid = tid >> 6, lid = tid & 63;
    if (lid == 0) red[wid] = cnt;
    __syncthreads();
    if (tid == 0) {
        int s = 0;
        for (int w = 0; w < 16; ++w) s += red[w];
        scalars[0] = (float)s;
    }
}

// ---------- kernel 1: main gather-accumulate ----------
// Pipeline per position: barrier1 -> issue pkA,L0 -> gather(0..13) -> issue pkB
// -> gather(14..27) -> pack L0, issue L1 -> gather(28..48) -> barrier2 -> commit.
// FIFO vmcnt discipline: every wait targets loads OLDER than anything still wanted
// in flight, so row prefetch stays outstanding through the whole gather phase.
__global__ __launch_bounds__(TPB) void k_main(
    const float* __restrict__ probs,
    const unsigned char* __restrict__ mask,
    const uint32_t* __restrict__ ppk,
    float* __restrict__ partials, int S, int direct)
{
    __shared__ __align__(16) ushort rows[2][V_];   // 125 KB: two bf16 rows (parity slots)
    __shared__ unsigned char mask_s[32];
    const int tid = threadIdx.x;
    const int g = blockIdx.x;
    const int n0 = g * POS_PER_BLK;
    const int n1 = min(N_, n0 + POS_PER_BLK);

    int r0 = n0 + n0 / (T_ - 1);     // row0(n) = n + n/(T-1)
    int r1 = r0 + 1;
    const int rbase = r0;
    {
        int rlast = (n1 - 1) + (n1 - 1) / (T_ - 1) + 1;
        int nrows = rlast - rbase + 1;            // <= 18
        if (tid < nrows) mask_s[tid] = mask[rbase + tid];
    }

    float acc[U_];
#pragma unroll
    for (int u = 0; u < U_; ++u) acc[u] = 0.f;

    stage_row(probs, r0, rows[r0 & 1], tid);
    stage_row(probs, r1, rows[r1 & 1], tid);

    const uint32_t* pp = ppk + tid;

    for (int n = n0; n < n1; ++n) {
        const int nn = n + 1;
        const bool more = (nn < n1);
        const int nr0 = nn + nn / (T_ - 1);
        const int nr1 = nr0 + 1;
        // normal: nr0==r1 -> prefetch nr1; batch boundary: prefetch nr0, sync-stage nr1
        const int pre_row = more ? ((nr0 == r1) ? nr1 : nr0) : -1;
        const bool extra = more && (nr0 != r1);
        const int ld_row = (pre_row >= 0) ? pre_row : 0;
        const float4* src = (const float4*)(probs + (size_t)ld_row * V_);

        __syncthreads();                           // barrier1: staged rows visible

        // [1] issue pair-index loads, chunks 0..3 (oldest in vmcnt FIFO)
        uint32_t pkA[28];
#pragma unroll
        for (int j = 0; j < 28; ++j) pkA[j] = pp[j * TPB];
        __builtin_amdgcn_sched_barrier(0);
        // [2] issue row prefetch, half 0 (stays in flight through gathers)
        float4 L0[4];
#pragma unroll
        for (int j = 0; j < 4; ++j) L0[j] = src[tid + j * TPB];
        __builtin_amdgcn_sched_barrier(0);

        const bool active = mask_s[r0 - rbase] && mask_s[r1 - rbase];
        const char* rp = (const char*)rows[r0 & 1];
        const char* rq = (const char*)rows[r1 & 1];

        // [3] gather pairs 0..13 (waits only pkA prefix)
        if (active) {
#pragma unroll
            for (int j = 0; j < 14; ++j) GATHER(pkA[j], acc[j]);
        }
        // [4] issue pair-index loads, chunks 4..6 (younger than L0)
        uint32_t pkB[21];
#pragma unroll
        for (int j = 0; j < 21; ++j) pkB[j] = pp[(28 + j) * TPB];
        __builtin_amdgcn_sched_barrier(0);
        // [5] gather pairs 14..27
        if (active) {
#pragma unroll
            for (int j = 14; j < 28; ++j) GATHER(pkA[j], acc[j]);
        }
        // [6] pack half 0 (waits L0; pkB is younger -> untouched)
        uint2 P0[4];
#pragma unroll
        for (int j = 0; j < 4; ++j) P0[j] = pack4(L0[j]);
        // [7] issue row prefetch, half 1 (youngest)
        float4 L1[4];
#pragma unroll
        for (int j = 0; j < 4; ++j) {
            int i = tid + (4 + j) * TPB;
            L1[j] = src[(i < W4) ? i : 0];
        }
        __builtin_amdgcn_sched_barrier(0);
        // [8] gather pairs 28..48 (waits pkB; L1 younger -> stays in flight)
        if (active) {
#pragma unroll
            for (int j = 0; j < 21; ++j) GATHER(pkB[j], acc[28 + j]);
        }

        __syncthreads();                           // barrier2: gathers done; L1 ~done

        // [9] commit prefetched row into freed slot
        if (pre_row >= 0) {
            ushort* dst = rows[pre_row & 1];
#pragma unroll
            for (int j = 0; j < 4; ++j)
                *(uint2*)(dst + (tid + j * TPB) * 4) = P0[j];
#pragma unroll
            for (int j = 0; j < 4; ++j) {
                int i = tid + (4 + j) * TPB;
                if (i < W4) *(uint2*)(dst + i * 4) = pack4(L1[j]);
            }
            if (extra) stage_row(probs, nr1, rows[nr1 & 1], tid);  // 3 blocks, once
        }
        r0 = nr0; r1 = nr1;
    }

    if (direct) {       // private slot per block: plain coalesced stores, no atomics
        float* slot = partials + (size_t)g * KP;
#pragma unroll
        for (int u = 0; u < U_; ++u) slot[u * TPB + tid] = acc[u];
    } else {
        float* slot = partials + (size_t)(g % S) * KP;
#pragma unroll
        for (int u = 0; u < U_; ++u) atomicAdd(slot + u * TPB + tid, acc[u]);
    }
}

// ---------- kernel 2: per-slot reduce + KL terms (slot -> pair via perm) ----------
__global__ void k_reduce(const float* __restrict__ partials, const uint32_t* __restrict__ perm,
                         const float* __restrict__ tgt,
                         float* __restrict__ scalars, int S) {
    int si = blockIdx.x * 256 + threadIdx.x;
    float n = fmaxf(scalars[0], 1.0f);
    float mt = 0.f, term = 0.f;
    if (si < KP) {
        uint32_t k = perm[si];
        if (k != PINV) {
            float ts = 0.f;
            for (int s = 0; s < S; ++s) ts += partials[(size_t)s * KP + si];
            mt = fmaxf(ts / n, EPSMOD);
            float tg = fmaxf(tgt[k], EPSTGT);
            term = mt * (__logf(mt) - __logf(tg));
        }
    }
    for (int off = 32; off > 0; off >>= 1) {
        mt += __shfl_down(mt, off, 64);
        term += __shfl_down(term, off, 64);
    }
    __shared__ float rm[4], rt[4];
    int wid = threadIdx.x >> 6, lid = threadIdx.x & 63;
    if (lid == 0) { rm[wid] = mt; rt[wid] = term; }
    __syncthreads();
    if (threadIdx.x == 0) {
        float sm = 0.f, st = 0.f;
        for (int w = 0; w < 4; ++w) { sm += rm[w]; st += rt[w]; }
        atomicAdd(&scalars[1], sm);   // sum of model_top
        atomicAdd(&scalars[2], st);   // kl_top
    }
}

// ---------- kernel 3: scalar epilogue ----------
__global__ void k_final(const float* __restrict__ scalars, const float* __restrict__ toov,
                        float* __restrict__ out) {
    float S1 = scalars[1], S2 = scalars[2];
    float moov = 1.f - S1;
    moov = fminf(fmaxf(moov, EPSMOD), 1.f - EPSTGT);
    float tv = fmaxf(toov[0], EPSTGT);
    out[0] = S2 + moov * (__logf(moov) - __logf(tv));
}

extern "C" void kernel_launch(void* const* d_in, const int* in_sizes, int n_in,
                              void* d_out, int out_size, void* d_ws, size_t ws_size,
                              hipStream_t stream) {
    const float* probs = (const float*)d_in[0];
    const float* tgt   = (const float*)d_in[1];
    const float* toov  = (const float*)d_in[2];
    const unsigned char* mask = (const unsigned char*)d_in[3];
    const int* pairs   = (const int*)d_in[4];
    float* out = (float*)d_out;

    char* ws = (char*)d_ws;
    // layout (all 256-aligned):
    uint32_t* ppk   = (uint32_t*)(ws + 0);          // KP u32        @0       (200704)
    uint32_t* perm  = (uint32_t*)(ws + 200704);     // KP u32                 (200704)
    uint32_t* ovf   = (uint32_t*)(ws + 401408);     // 2*K_ u32 worst-case    (400128)
    uint32_t* holes = (uint32_t*)(ws + 801536);     // KP u32                 (200704)
    size_t off_sc = 1002240;
    float* scalars = (float*)(ws + off_sc);          // [0]=n_pairs [1]=S1 [2]=S2
    size_t off_pt = off_sc + 256;
    float* partials = (float*)(ws + off_pt);

    long avail = (long)ws_size - (long)off_pt;
    int smax = (int)(avail / ((long)KP * 4));
    int direct = (smax >= G1) ? 1 : 0;
    int S = direct ? G1 : (smax < 1 ? 1 : (smax > 64 ? 64 : smax));

    // scalars always zeroed; partials only when accumulated via atomics
    hipMemsetAsync(ws + off_sc, 0, 256, stream);
    if (!direct) hipMemsetAsync(partials, 0, (size_t)S * KP * 4, stream);
    k_perm<<<1, 1024, 0, stream>>>(pairs, ppk, perm, ovf, holes);
    k_mask<<<1, 1024, 0, stream>>>(mask, scalars);
    k_main<<<G1, TPB, 0, stream>>>(probs, mask, ppk, partials, S, direct);
    k_reduce<<<(KP + 255) / 256, 256, 0, stream>>>(partials, perm, tgt, scalars, S);
    k_final<<<1, 1, 0, stream>>>(scalars, toov, out);
}

// Round 2
// 792.954 us; speedup vs baseline: 1.1061x; 1.1061x over previous
//
#include <hip/hip_runtime.h>
#include <stdint.h>

#define B_   4
#define T_   1024
#define V_   32000
#define K_   50000
#define N_   (B_*(T_-1))        // 4092 pair-positions
#define TPB  1024
#define U_   49                  // ceil(K_/TPB)
#define KP   (TPB*U_)            // 50176 padded K
#define POS_PER_BLK 16
#define G1   ((N_ + POS_PER_BLK - 1)/POS_PER_BLK)   // 256 blocks = 1/CU (125KB LDS)
#define EPSTGT 1e-8f
#define EPSMOD 1e-12f
#define W4   (V_/4)              // 8000 float4 per row
#define NGRP (KP/64)             // 784 gather groups of 64 lanes
#define SCAP (2*NGRP)            // 1568: structured capacity per a-bank bin
#define PINV 0xFFFFFFFFu
#define NBLK_P 64                // blocks for the perm-build pipeline

// ---------- helpers ----------
__device__ __forceinline__ uint32_t bf16rne(float x) {
    uint32_t u = __float_as_uint(x);
    u += 0x7FFFu + ((u >> 16) & 1u);
    return u >> 16;
}
__device__ __forceinline__ uint2 pack4(float4 v) {
    uint2 pk;
    pk.x = bf16rne(v.x) | (bf16rne(v.y) << 16);
    pk.y = bf16rne(v.z) | (bf16rne(v.w) << 16);
    return pk;
}
// synchronous stage: fp32 global row -> bf16 LDS row (prologue / batch-boundary only)
__device__ __forceinline__ void stage_row(const float* __restrict__ probs, int r,
                                          ushort* dst, int tid) {
    const float4* src = (const float4*)(probs + (size_t)r * V_);
    for (int i = tid; i < W4; i += TPB) {
        *(uint2*)(dst + i * 4) = pack4(src[i]);
    }
}

// gather one pair: 2 LDS bf16 reads + fma
#define GATHER(pkv, accv) do {                                          \
    uint32_t ao_ = (pkv) >> 16, bo_ = (pkv) & 0xFFFFu;                  \
    ushort av_ = *(const ushort*)(rp + ao_);                            \
    ushort bv_ = *(const ushort*)(rq + bo_);                            \
    accv = fmaf(__uint_as_float((uint32_t)av_ << 16),                   \
                __uint_as_float((uint32_t)bv_ << 16), accv);            \
} while (0)

// ---------- perm-build pipeline (parallel, replaces round-1 single-block k_perm) ----------
// Slot s = group*64 + lane; k_main's gather reads one full group per wave-instruction.
// Counting-sort pairs by a-bank (a>>1)&31 -> lanes {w, w+32} carry bin w:
//   every a-read instruction is exactly 2 lanes/bank (free, m136).
// Within each bin, order by b-bank and rotate bin w by w*len/32:
//   group g samples 32 staggered b-quantiles -> b-banks ~(X-w) mod 32, also 2/bank.
// Bin overflow past SCAP spills into the pad/underfull holes (few hundred items).

// P0: zero-init handled by memset; init ppk/perm stripes + (a-bank,b-bank) histogram
__global__ __launch_bounds__(1024) void k_hist(const int* __restrict__ pairs,
                                               uint32_t* __restrict__ hist,
                                               uint32_t* __restrict__ ppk,
                                               uint32_t* __restrict__ perm) {
    int tid = blockIdx.x * 1024 + threadIdx.x;
    for (int s = tid; s < KP; s += NBLK_P * 1024) { ppk[s] = 0; perm[s] = PINV; }
    for (int k = tid; k < K_; k += NBLK_P * 1024) {
        uint32_t a = (uint32_t)pairs[2 * k];
        uint32_t b = (uint32_t)pairs[2 * k + 1];
        atomicAdd(&hist[(((a >> 1) & 31) << 5) + ((b >> 1) & 31)], 1u);
    }
}

// P1: per-bin prefix (b-bank order) + bin counts + rotations; also n_pairs from mask
__global__ __launch_bounds__(1024) void k_prefmask(const uint32_t* __restrict__ hist,
                                                   uint32_t* __restrict__ boff,
                                                   uint32_t* __restrict__ meta,
                                                   const unsigned char* __restrict__ mask,
                                                   float* __restrict__ scalars) {
    int tid = threadIdx.x;
    if (tid < 32) {
        uint32_t s = 0;
        for (int j = 0; j < 32; ++j) { boff[(tid << 5) + j] = s; s += hist[(tid << 5) + j]; }
        meta[tid] = s;                               // binc[w]
        meta[32 + tid] = ((uint32_t)tid * s) >> 5;   // rot[w] = w*len/32
    }
    // independent: n_pairs from mask
    __shared__ int red[16];
    int cnt = 0;
    for (int n = tid; n < N_; n += 1024) {
        int b = n / (T_ - 1);
        int t = n - b * (T_ - 1);
        int r = b * T_ + t;
        cnt += (mask[r] && mask[r + 1]) ? 1 : 0;
    }
    for (int off = 32; off > 0; off >>= 1) cnt += __shfl_down(cnt, off, 64);
    int wid = tid >> 6, lid = tid & 63;
    if (lid == 0) red[wid] = cnt;
    __syncthreads();
    if (tid == 0) {
        int s = 0;
        for (int w = 0; w < 16; ++w) s += red[w];
        scalars[0] = (float)s;
    }
}

// P2: scatter pairs into structured slots (or overflow list)
__global__ __launch_bounds__(1024) void k_scatter(const int* __restrict__ pairs,
                                                  const uint32_t* __restrict__ boff,
                                                  uint32_t* __restrict__ cnt,
                                                  uint32_t* __restrict__ meta,
                                                  uint32_t* __restrict__ ppk,
                                                  uint32_t* __restrict__ perm,
                                                  uint32_t* __restrict__ ovf) {
    int tid = blockIdx.x * 1024 + threadIdx.x;
    for (int k = tid; k < K_; k += NBLK_P * 1024) {
        uint32_t a = (uint32_t)pairs[2 * k];
        uint32_t b = (uint32_t)pairs[2 * k + 1];
        uint32_t aw = (a >> 1) & 31, bw = (b >> 1) & 31;
        uint32_t j = boff[(aw << 5) + bw] + atomicAdd(&cnt[(aw << 5) + bw], 1u);
        uint32_t c = meta[aw];
        uint32_t jp = j + meta[32 + aw]; if (jp >= c) jp -= c;
        uint32_t pk = ((a * 2u) << 16) | (b * 2u);
        if (jp < SCAP) {
            uint32_t s = ((jp >> 1) << 6) + aw + ((jp & 1u) << 5);
            ppk[s] = pk; perm[s] = (uint32_t)k;
        } else {
            uint32_t i = atomicAdd(&meta[64], 1u);   // novf
            ovf[2 * i] = pk; ovf[2 * i + 1] = (uint32_t)k;
        }
    }
}

// P3: compact hole slots (pads + underfull tails); order irrelevant
__global__ __launch_bounds__(1024) void k_holes(const uint32_t* __restrict__ perm,
                                                uint32_t* __restrict__ meta,
                                                uint32_t* __restrict__ holes) {
    int tid = blockIdx.x * 1024 + threadIdx.x;
    for (int s = tid; s < KP; s += NBLK_P * 1024) {
        if (perm[s] == PINV) { uint32_t i = atomicAdd(&meta[65], 1u); holes[i] = (uint32_t)s; }
    }
}

// P4: place overflow items into holes (nhole >= novf by counting)
__global__ __launch_bounds__(1024) void k_fill(const uint32_t* __restrict__ holes,
                                               const uint32_t* __restrict__ ovf,
                                               const uint32_t* __restrict__ meta,
                                               uint32_t* __restrict__ ppk,
                                               uint32_t* __restrict__ perm) {
    uint32_t nv = meta[64];
    for (uint32_t i = threadIdx.x; i < nv; i += 1024) {
        uint32_t s = holes[i];
        ppk[s] = ovf[2 * i]; perm[s] = ovf[2 * i + 1];
    }
}

// ---------- kernel 1: main gather-accumulate (byte-identical to round 0/1) ----------
// Pipeline per position: barrier1 -> issue pkA,L0 -> gather(0..13) -> issue pkB
// -> gather(14..27) -> pack L0, issue L1 -> gather(28..48) -> barrier2 -> commit.
// FIFO vmcnt discipline: every wait targets loads OLDER than anything still wanted
// in flight, so row prefetch stays outstanding through the whole gather phase.
__global__ __launch_bounds__(TPB) void k_main(
    const float* __restrict__ probs,
    const unsigned char* __restrict__ mask,
    const uint32_t* __restrict__ ppk,
    float* __restrict__ partials, int S, int direct)
{
    __shared__ __align__(16) ushort rows[2][V_];   // 125 KB: two bf16 rows (parity slots)
    __shared__ unsigned char mask_s[32];
    const int tid = threadIdx.x;
    const int g = blockIdx.x;
    const int n0 = g * POS_PER_BLK;
    const int n1 = min(N_, n0 + POS_PER_BLK);

    int r0 = n0 + n0 / (T_ - 1);     // row0(n) = n + n/(T-1)
    int r1 = r0 + 1;
    const int rbase = r0;
    {
        int rlast = (n1 - 1) + (n1 - 1) / (T_ - 1) + 1;
        int nrows = rlast - rbase + 1;            // <= 18
        if (tid < nrows) mask_s[tid] = mask[rbase + tid];
    }

    float acc[U_];
#pragma unroll
    for (int u = 0; u < U_; ++u) acc[u] = 0.f;

    stage_row(probs, r0, rows[r0 & 1], tid);
    stage_row(probs, r1, rows[r1 & 1], tid);

    const uint32_t* pp = ppk + tid;

    for (int n = n0; n < n1; ++n) {
        const int nn = n + 1;
        const bool more = (nn < n1);
        const int nr0 = nn + nn / (T_ - 1);
        const int nr1 = nr0 + 1;
        // normal: nr0==r1 -> prefetch nr1; batch boundary: prefetch nr0, sync-stage nr1
        const int pre_row = more ? ((nr0 == r1) ? nr1 : nr0) : -1;
        const bool extra = more && (nr0 != r1);
        const int ld_row = (pre_row >= 0) ? pre_row : 0;
        const float4* src = (const float4*)(probs + (size_t)ld_row * V_);

        __syncthreads();                           // barrier1: staged rows visible

        // [1] issue pair-index loads, chunks 0..3 (oldest in vmcnt FIFO)
        uint32_t pkA[28];
#pragma unroll
        for (int j = 0; j < 28; ++j) pkA[j] = pp[j * TPB];
        __builtin_amdgcn_sched_barrier(0);
        // [2] issue row prefetch, half 0 (stays in flight through gathers)
        float4 L0[4];
#pragma unroll
        for (int j = 0; j < 4; ++j) L0[j] = src[tid + j * TPB];
        __builtin_amdgcn_sched_barrier(0);

        const bool active = mask_s[r0 - rbase] && mask_s[r1 - rbase];
        const char* rp = (const char*)rows[r0 & 1];
        const char* rq = (const char*)rows[r1 & 1];

        // [3] gather pairs 0..13 (waits only pkA prefix)
        if (active) {
#pragma unroll
            for (int j = 0; j < 14; ++j) GATHER(pkA[j], acc[j]);
        }
        // [4] issue pair-index loads, chunks 4..6 (younger than L0)
        uint32_t pkB[21];
#pragma unroll
        for (int j = 0; j < 21; ++j) pkB[j] = pp[(28 + j) * TPB];
        __builtin_amdgcn_sched_barrier(0);
        // [5] gather pairs 14..27
        if (active) {
#pragma unroll
            for (int j = 14; j < 28; ++j) GATHER(pkA[j], acc[j]);
        }
        // [6] pack half 0 (waits L0; pkB is younger -> untouched)
        uint2 P0[4];
#pragma unroll
        for (int j = 0; j < 4; ++j) P0[j] = pack4(L0[j]);
        // [7] issue row prefetch, half 1 (youngest)
        float4 L1[4];
#pragma unroll
        for (int j = 0; j < 4; ++j) {
            int i = tid + (4 + j) * TPB;
            L1[j] = src[(i < W4) ? i : 0];
        }
        __builtin_amdgcn_sched_barrier(0);
        // [8] gather pairs 28..48 (waits pkB; L1 younger -> stays in flight)
        if (active) {
#pragma unroll
            for (int j = 0; j < 21; ++j) GATHER(pkB[j], acc[28 + j]);
        }

        __syncthreads();                           // barrier2: gathers done; L1 ~done

        // [9] commit prefetched row into freed slot
        if (pre_row >= 0) {
            ushort* dst = rows[pre_row & 1];
#pragma unroll
            for (int j = 0; j < 4; ++j)
                *(uint2*)(dst + (tid + j * TPB) * 4) = P0[j];
#pragma unroll
            for (int j = 0; j < 4; ++j) {
                int i = tid + (4 + j) * TPB;
                if (i < W4) *(uint2*)(dst + i * 4) = pack4(L1[j]);
            }
            if (extra) stage_row(probs, nr1, rows[nr1 & 1], tid);  // 3 blocks, once
        }
        r0 = nr0; r1 = nr1;
    }

    if (direct) {       // private slot per block: plain coalesced stores, no atomics
        float* slot = partials + (size_t)g * KP;
#pragma unroll
        for (int u = 0; u < U_; ++u) slot[u * TPB + tid] = acc[u];
    } else {
        float* slot = partials + (size_t)(g % S) * KP;
#pragma unroll
        for (int u = 0; u < U_; ++u) atomicAdd(slot + u * TPB + tid, acc[u]);
    }
}

// ---------- kernel 2: per-slot reduce + KL terms (slot -> pair via perm) ----------
__global__ void k_reduce(const float* __restrict__ partials, const uint32_t* __restrict__ perm,
                         const float* __restrict__ tgt,
                         float* __restrict__ scalars, int S) {
    int si = blockIdx.x * 256 + threadIdx.x;
    float n = fmaxf(scalars[0], 1.0f);
    float mt = 0.f, term = 0.f;
    if (si < KP) {
        uint32_t k = perm[si];
        if (k != PINV) {
            float ts = 0.f;
            for (int s = 0; s < S; ++s) ts += partials[(size_t)s * KP + si];
            mt = fmaxf(ts / n, EPSMOD);
            float tg = fmaxf(tgt[k], EPSTGT);
            term = mt * (__logf(mt) - __logf(tg));
        }
    }
    for (int off = 32; off > 0; off >>= 1) {
        mt += __shfl_down(mt, off, 64);
        term += __shfl_down(term, off, 64);
    }
    __shared__ float rm[4], rt[4];
    int wid = threadIdx.x >> 6, lid = threadIdx.x & 63;
    if (lid == 0) { rm[wid] = mt; rt[wid] = term; }
    __syncthreads();
    if (threadIdx.x == 0) {
        float sm = 0.f, st = 0.f;
        for (int w = 0; w < 4; ++w) { sm += rm[w]; st += rt[w]; }
        atomicAdd(&scalars[1], sm);   // sum of model_top
        atomicAdd(&scalars[2], st);   // kl_top
    }
}

// ---------- kernel 3: scalar epilogue ----------
__global__ void k_final(const float* __restrict__ scalars, const float* __restrict__ toov,
                        float* __restrict__ out) {
    float S1 = scalars[1], S2 = scalars[2];
    float moov = 1.f - S1;
    moov = fminf(fmaxf(moov, EPSMOD), 1.f - EPSTGT);
    float tv = fmaxf(toov[0], EPSTGT);
    out[0] = S2 + moov * (__logf(moov) - __logf(tv));
}

extern "C" void kernel_launch(void* const* d_in, const int* in_sizes, int n_in,
                              void* d_out, int out_size, void* d_ws, size_t ws_size,
                              hipStream_t stream) {
    const float* probs = (const float*)d_in[0];
    const float* tgt   = (const float*)d_in[1];
    const float* toov  = (const float*)d_in[2];
    const unsigned char* mask = (const unsigned char*)d_in[3];
    const int* pairs   = (const int*)d_in[4];
    float* out = (float*)d_out;

    char* ws = (char*)d_ws;
    // layout (all 256-aligned):
    uint32_t* ppk   = (uint32_t*)(ws + 0);          // KP u32                (200704)
    uint32_t* perm  = (uint32_t*)(ws + 200704);     // KP u32                (200704)
    uint32_t* ovf   = (uint32_t*)(ws + 401408);     // 2*K_ u32 worst case   (400000)
    uint32_t* holes = (uint32_t*)(ws + 801536);     // KP u32                (200704)
    uint32_t* hist  = (uint32_t*)(ws + 1002240);    // 1024 u32
    uint32_t* boff  = (uint32_t*)(ws + 1006336);    // 1024 u32
    uint32_t* cnt   = (uint32_t*)(ws + 1010432);    // 1024 u32
    uint32_t* meta  = (uint32_t*)(ws + 1014528);    // [0:32)=binc [32:64)=rot [64]=novf [65]=nhole
    size_t off_sc = 1015040;
    float* scalars = (float*)(ws + off_sc);          // [0]=n_pairs [1]=S1 [2]=S2
    size_t off_pt = 1015296;
    float* partials = (float*)(ws + off_pt);

    long avail = (long)ws_size - (long)off_pt;
    int smax = (int)(avail / ((long)KP * 4));
    int direct = (smax >= G1) ? 1 : 0;
    int S = direct ? G1 : (smax < 1 ? 1 : (smax > 64 ? 64 : smax));

    // one memset covers hist/boff/cnt/meta/scalars control area
    hipMemsetAsync(ws + 1002240, 0, off_pt - 1002240, stream);
    if (!direct) hipMemsetAsync(partials, 0, (size_t)S * KP * 4, stream);

    k_hist    <<<NBLK_P, 1024, 0, stream>>>(pairs, hist, ppk, perm);
    k_prefmask<<<1, 1024, 0, stream>>>(hist, boff, meta, mask, scalars);
    k_scatter <<<NBLK_P, 1024, 0, stream>>>(pairs, boff, cnt, meta, ppk, perm, ovf);
    k_holes   <<<NBLK_P, 1024, 0, stream>>>(perm, meta, holes);
    k_fill    <<<1, 1024, 0, stream>>>(holes, ovf, meta, ppk, perm);
    k_main    <<<G1, TPB, 0, stream>>>(probs, mask, ppk, partials, S, direct);
    k_reduce  <<<(KP + 255) / 256, 256, 0, stream>>>(partials, perm, tgt, scalars, S);
    k_final   <<<1, 1, 0, stream>>>(scalars, toov, out);
}

// Round 3
// 763.533 us; speedup vs baseline: 1.1487x; 1.0385x over previous
//
#include <hip/hip_runtime.h>
#include <stdint.h>

#define B_   4
#define T_   1024
#define V_   32000
#define K_   50000
#define N_   (B_*(T_-1))        // 4092 pair-positions
#define TPB  1024
#define U_   49                  // ceil(K_/TPB)
#define KP   (TPB*U_)            // 50176 padded K
#define POS_PER_BLK 16
#define G1   ((N_ + POS_PER_BLK - 1)/POS_PER_BLK)   // 256 blocks = 1/CU (125KB LDS)
#define EPSTGT 1e-8f
#define EPSMOD 1e-12f
#define W4   (V_/4)              // 8000 float4 per row
#define RBLK (KP/256)            // 196 reduce blocks (KP = 196*256 exactly)

// ---------- helpers ----------
__device__ __forceinline__ uint32_t bf16rne(float x) {
    uint32_t u = __float_as_uint(x);
    u += 0x7FFFu + ((u >> 16) & 1u);
    return u >> 16;
}
__device__ __forceinline__ uint2 pack4(float4 v) {
    uint2 pk;
    pk.x = bf16rne(v.x) | (bf16rne(v.y) << 16);
    pk.y = bf16rne(v.z) | (bf16rne(v.w) << 16);
    return pk;
}
// synchronous stage: fp32 global row -> bf16 LDS row (prologue / batch-boundary only)
__device__ __forceinline__ void stage_row(const float* __restrict__ probs, int r,
                                          ushort* dst, int tid) {
    const float4* src = (const float4*)(probs + (size_t)r * V_);
    for (int i = tid; i < W4; i += TPB) {
        *(uint2*)(dst + i * 4) = pack4(src[i]);
    }
}

// gather one pair: 2 LDS bf16 reads + fma
#define GATHER(pkv, accv) do {                                          \
    uint32_t ao_ = (pkv) >> 16, bo_ = (pkv) & 0xFFFFu;                  \
    ushort av_ = *(const ushort*)(rp + ao_);                            \
    ushort bv_ = *(const ushort*)(rq + bo_);                            \
    accv = fmaf(__uint_as_float((uint32_t)av_ << 16),                   \
                __uint_as_float((uint32_t)bv_ << 16), accv);            \
} while (0)

// ---------- kernel A: pack pair indices + mask count + zero control scalars ----------
// pairs packed as bf16-byte-offsets (a*2)<<16 | (b*2); pads -> 0 (harmless gather).
// Block 0 additionally: counts valid pairs into scalars[0], zeroes scalars[1..3].
__global__ __launch_bounds__(1024) void k_pre(const int* __restrict__ pairs,
                                              const unsigned char* __restrict__ mask,
                                              uint32_t* __restrict__ ppk,
                                              float* __restrict__ scalars) {
    int tid = blockIdx.x * 1024 + threadIdx.x;
    for (int k = tid; k < KP; k += 64 * 1024) {
        uint32_t v = 0;
        if (k < K_) {
            uint32_t a = (uint32_t)pairs[2 * k];
            uint32_t b = (uint32_t)pairs[2 * k + 1];
            v = ((a * 2u) << 16) | (b * 2u);
        }
        ppk[k] = v;
    }
    if (blockIdx.x == 0) {
        __shared__ int red[16];
        int t = threadIdx.x;
        int cnt = 0;
        for (int n = t; n < N_; n += 1024) {
            int b = n / (T_ - 1);
            int tt = n - b * (T_ - 1);
            int r = b * T_ + tt;
            cnt += (mask[r] && mask[r + 1]) ? 1 : 0;
        }
        for (int off = 32; off > 0; off >>= 1) cnt += __shfl_down(cnt, off, 64);
        int wid = t >> 6, lid = t & 63;
        if (lid == 0) red[wid] = cnt;
        __syncthreads();
        if (t == 0) {
            int s = 0;
            for (int w = 0; w < 16; ++w) s += red[w];
            scalars[0] = (float)s;
            scalars[1] = 0.f;      // sum model_top
            scalars[2] = 0.f;      // kl_top
            ((int*)scalars)[3] = 0; // ticket
        }
    }
}

// ---------- kernel B: main gather-accumulate (byte-identical to round 0) ----------
// Pipeline per position: barrier1 -> issue pkA,L0 -> gather(0..13) -> issue pkB
// -> gather(14..27) -> pack L0, issue L1 -> gather(28..48) -> barrier2 -> commit.
// FIFO vmcnt discipline: every wait targets loads OLDER than anything still wanted
// in flight, so row prefetch stays outstanding through the whole gather phase.
__global__ __launch_bounds__(TPB) void k_main(
    const float* __restrict__ probs,
    const unsigned char* __restrict__ mask,
    const uint32_t* __restrict__ ppk,
    float* __restrict__ partials, int S, int direct)
{
    __shared__ __align__(16) ushort rows[2][V_];   // 125 KB: two bf16 rows (parity slots)
    __shared__ unsigned char mask_s[32];
    const int tid = threadIdx.x;
    const int g = blockIdx.x;
    const int n0 = g * POS_PER_BLK;
    const int n1 = min(N_, n0 + POS_PER_BLK);

    int r0 = n0 + n0 / (T_ - 1);     // row0(n) = n + n/(T-1)
    int r1 = r0 + 1;
    const int rbase = r0;
    {
        int rlast = (n1 - 1) + (n1 - 1) / (T_ - 1) + 1;
        int nrows = rlast - rbase + 1;            // <= 18
        if (tid < nrows) mask_s[tid] = mask[rbase + tid];
    }

    float acc[U_];
#pragma unroll
    for (int u = 0; u < U_; ++u) acc[u] = 0.f;

    stage_row(probs, r0, rows[r0 & 1], tid);
    stage_row(probs, r1, rows[r1 & 1], tid);

    const uint32_t* pp = ppk + tid;

    for (int n = n0; n < n1; ++n) {
        const int nn = n + 1;
        const bool more = (nn < n1);
        const int nr0 = nn + nn / (T_ - 1);
        const int nr1 = nr0 + 1;
        // normal: nr0==r1 -> prefetch nr1; batch boundary: prefetch nr0, sync-stage nr1
        const int pre_row = more ? ((nr0 == r1) ? nr1 : nr0) : -1;
        const bool extra = more && (nr0 != r1);
        const int ld_row = (pre_row >= 0) ? pre_row : 0;
        const float4* src = (const float4*)(probs + (size_t)ld_row * V_);

        __syncthreads();                           // barrier1: staged rows visible

        // [1] issue pair-index loads, chunks 0..3 (oldest in vmcnt FIFO)
        uint32_t pkA[28];
#pragma unroll
        for (int j = 0; j < 28; ++j) pkA[j] = pp[j * TPB];
        __builtin_amdgcn_sched_barrier(0);
        // [2] issue row prefetch, half 0 (stays in flight through gathers)
        float4 L0[4];
#pragma unroll
        for (int j = 0; j < 4; ++j) L0[j] = src[tid + j * TPB];
        __builtin_amdgcn_sched_barrier(0);

        const bool active = mask_s[r0 - rbase] && mask_s[r1 - rbase];
        const char* rp = (const char*)rows[r0 & 1];
        const char* rq = (const char*)rows[r1 & 1];

        // [3] gather pairs 0..13 (waits only pkA prefix)
        if (active) {
#pragma unroll
            for (int j = 0; j < 14; ++j) GATHER(pkA[j], acc[j]);
        }
        // [4] issue pair-index loads, chunks 4..6 (younger than L0)
        uint32_t pkB[21];
#pragma unroll
        for (int j = 0; j < 21; ++j) pkB[j] = pp[(28 + j) * TPB];
        __builtin_amdgcn_sched_barrier(0);
        // [5] gather pairs 14..27
        if (active) {
#pragma unroll
            for (int j = 14; j < 28; ++j) GATHER(pkA[j], acc[j]);
        }
        // [6] pack half 0 (waits L0; pkB is younger -> untouched)
        uint2 P0[4];
#pragma unroll
        for (int j = 0; j < 4; ++j) P0[j] = pack4(L0[j]);
        // [7] issue row prefetch, half 1 (youngest)
        float4 L1[4];
#pragma unroll
        for (int j = 0; j < 4; ++j) {
            int i = tid + (4 + j) * TPB;
            L1[j] = src[(i < W4) ? i : 0];
        }
        __builtin_amdgcn_sched_barrier(0);
        // [8] gather pairs 28..48 (waits pkB; L1 younger -> stays in flight)
        if (active) {
#pragma unroll
            for (int j = 0; j < 21; ++j) GATHER(pkB[j], acc[28 + j]);
        }

        __syncthreads();                           // barrier2: gathers done; L1 ~done

        // [9] commit prefetched row into freed slot
        if (pre_row >= 0) {
            ushort* dst = rows[pre_row & 1];
#pragma unroll
            for (int j = 0; j < 4; ++j)
                *(uint2*)(dst + (tid + j * TPB) * 4) = P0[j];
#pragma unroll
            for (int j = 0; j < 4; ++j) {
                int i = tid + (4 + j) * TPB;
                if (i < W4) *(uint2*)(dst + i * 4) = pack4(L1[j]);
            }
            if (extra) stage_row(probs, nr1, rows[nr1 & 1], tid);  // 3 blocks, once
        }
        r0 = nr0; r1 = nr1;
    }

    if (direct) {       // private slot per block: plain coalesced stores, no atomics
        float* slot = partials + (size_t)g * KP;
#pragma unroll
        for (int u = 0; u < U_; ++u) slot[u * TPB + tid] = acc[u];
    } else {
        float* slot = partials + (size_t)(g % S) * KP;
#pragma unroll
        for (int u = 0; u < U_; ++u) atomicAdd(slot + u * TPB + tid, acc[u]);
    }
}

// ---------- kernel C: per-k reduce + KL terms + fused scalar epilogue ----------
// Each block reduces its 256 slots, atomically adds its two partial sums, then the
// last-arriving block (ticket) computes the final output. Device-scope atomics;
// __threadfence orders the sum-adds before the ticket increment.
__global__ __launch_bounds__(256) void k_post(const float* __restrict__ partials,
                                              const float* __restrict__ tgt,
                                              const float* __restrict__ toov,
                                              float* __restrict__ scalars,
                                              float* __restrict__ out, int S) {
    int k = blockIdx.x * 256 + threadIdx.x;     // < KP always (grid = KP/256)
    float n = fmaxf(scalars[0], 1.0f);
    float mt = 0.f, term = 0.f;
    if (k < K_) {
        float ts = 0.f;
        for (int s = 0; s < S; ++s) ts += partials[(size_t)s * KP + k];
        mt = fmaxf(ts / n, EPSMOD);
        float tg = fmaxf(tgt[k], EPSTGT);
        term = mt * (__logf(mt) - __logf(tg));
    }
    for (int off = 32; off > 0; off >>= 1) {
        mt += __shfl_down(mt, off, 64);
        term += __shfl_down(term, off, 64);
    }
    __shared__ float rm[4], rt[4];
    int wid = threadIdx.x >> 6, lid = threadIdx.x & 63;
    if (lid == 0) { rm[wid] = mt; rt[wid] = term; }
    __syncthreads();
    if (threadIdx.x == 0) {
        float sm = rm[0] + rm[1] + rm[2] + rm[3];
        float st = rt[0] + rt[1] + rt[2] + rt[3];
        atomicAdd(&scalars[1], sm);   // sum of model_top
        atomicAdd(&scalars[2], st);   // kl_top
        __threadfence();              // order sum-adds before ticket
        int old = atomicAdd((int*)&scalars[3], 1);
        if (old == RBLK - 1) {        // last block: all adds visible
            float S1 = atomicAdd(&scalars[1], 0.f);   // device-scope read
            float S2 = atomicAdd(&scalars[2], 0.f);
            float moov = 1.f - S1;
            moov = fminf(fmaxf(moov, EPSMOD), 1.f - EPSTGT);
            float tv = fmaxf(toov[0], EPSTGT);
            out[0] = S2 + moov * (__logf(moov) - __logf(tv));
        }
    }
}

extern "C" void kernel_launch(void* const* d_in, const int* in_sizes, int n_in,
                              void* d_out, int out_size, void* d_ws, size_t ws_size,
                              hipStream_t stream) {
    const float* probs = (const float*)d_in[0];
    const float* tgt   = (const float*)d_in[1];
    const float* toov  = (const float*)d_in[2];
    const unsigned char* mask = (const unsigned char*)d_in[3];
    const int* pairs   = (const int*)d_in[4];
    float* out = (float*)d_out;

    char* ws = (char*)d_ws;
    uint32_t* ppk = (uint32_t*)ws;                   // KP u32 = 200704 B
    float* scalars = (float*)(ws + 200704);          // [0]=n_pairs [1]=S1 [2]=S2 [3]=ticket
    float* partials = (float*)(ws + 200960);         // 256-aligned

    long avail = (long)ws_size - 200960;
    int smax = (int)(avail / ((long)KP * 4));
    int direct = (smax >= G1) ? 1 : 0;
    int S = direct ? G1 : (smax < 1 ? 1 : (smax > 64 ? 64 : smax));

    if (!direct) hipMemsetAsync(partials, 0, (size_t)S * KP * 4, stream);  // unlikely path

    k_pre <<<64, 1024, 0, stream>>>(pairs, mask, ppk, scalars);
    k_main<<<G1, TPB, 0, stream>>>(probs, mask, ppk, partials, S, direct);
    k_post<<<RBLK, 256, 0, stream>>>(partials, tgt, toov, scalars, out, S);
}